// Round 7
// baseline (946.933 us; speedup 1.0000x reference)
//
#include <hip/hip_runtime.h>

typedef unsigned short bf16_t;
typedef __attribute__((ext_vector_type(8))) short bf16x8;
typedef __attribute__((ext_vector_type(4))) float f32x4;

// ---------------- conversions ----------------
__device__ __forceinline__ float bf2f(bf16_t u) {
  union { unsigned int i; float f; } v; v.i = ((unsigned int)u) << 16; return v.f;
}
__device__ __forceinline__ bf16_t f2bf(float f) {
  union { float f; unsigned int i; } v; v.f = f;
  unsigned int u = v.i;
  u += 0x7fffu + ((u >> 16) & 1u);   // RNE
  return (bf16_t)(u >> 16);
}
__device__ __forceinline__ float gelu_exact(float x) {
  return 0.5f * x * (1.0f + erff(x * 0.7071067811865475f));
}

// ---------------- fp32 -> bf16 convert ----------------
__global__ __launch_bounds__(256) void f2bf_kernel(const float4* __restrict__ s,
                                                   ushort4* __restrict__ d, int n4) {
  int i = blockIdx.x * 256 + threadIdx.x;
  if (i < n4) {
    float4 f = s[i];
    ushort4 u; u.x = f2bf(f.x); u.y = f2bf(f.y); u.z = f2bf(f.z); u.w = f2bf(f.w);
    d[i] = u;
  }
}

// ---------------- LayerNorm: one wave per row of 512, fp32 in -> bf16 out ----------------
__global__ __launch_bounds__(256) void ln_kernel(const float* __restrict__ x,
                                                 const float* __restrict__ g,
                                                 const float* __restrict__ bta,
                                                 bf16_t* __restrict__ y) {
  const int w = threadIdx.x >> 6, lane = threadIdx.x & 63;
  const long row = (long)blockIdx.x * 4 + w;
  const long base = row * 512;
  const int c0 = lane << 2;
  float v[8];
  float4 f0 = *(const float4*)(x + base + c0);
  float4 f1 = *(const float4*)(x + base + 256 + c0);
  v[0]=f0.x; v[1]=f0.y; v[2]=f0.z; v[3]=f0.w;
  v[4]=f1.x; v[5]=f1.y; v[6]=f1.z; v[7]=f1.w;
  float s = 0.f;
#pragma unroll
  for (int c=0;c<8;++c) s += v[c];
#pragma unroll
  for (int o=32;o>0;o>>=1) s += __shfl_xor(s, o);
  const float mean = s * 0.001953125f;
  float ss = 0.f;
#pragma unroll
  for (int c=0;c<8;++c) { float d = v[c]-mean; ss += d*d; }
#pragma unroll
  for (int o=32;o>0;o>>=1) ss += __shfl_xor(ss, o);
  const float rstd = rsqrtf(ss * 0.001953125f + 1e-5f);
  ushort4 o0, o1;
  o0.x = f2bf((v[0]-mean)*rstd*g[c0+0] + bta[c0+0]);
  o0.y = f2bf((v[1]-mean)*rstd*g[c0+1] + bta[c0+1]);
  o0.z = f2bf((v[2]-mean)*rstd*g[c0+2] + bta[c0+2]);
  o0.w = f2bf((v[3]-mean)*rstd*g[c0+3] + bta[c0+3]);
  o1.x = f2bf((v[4]-mean)*rstd*g[256+c0+0] + bta[256+c0+0]);
  o1.y = f2bf((v[5]-mean)*rstd*g[256+c0+1] + bta[256+c0+1]);
  o1.z = f2bf((v[6]-mean)*rstd*g[256+c0+2] + bta[256+c0+2]);
  o1.w = f2bf((v[7]-mean)*rstd*g[256+c0+3] + bta[256+c0+3]);
  *(ushort4*)(y + base + c0) = o0;
  *(ushort4*)(y + base + 256 + c0) = o1;
}

// ---------------- MFMA GEMM  C = A @ W^T  (bf16 in, +bias/gelu/scale/+res fp32) ------------
// bf16 output goes through an LDS-staged coalesced epilogue (uint4 stores).
// Optional vt mode: columns >= vtC0 are written transposed per head into vtD
// as [b*vtNH + h][vtDH][vtN] (fuses the V^T transpose into the GEMM).
struct MmaNT {
  const bf16_t* A; const bf16_t* W; const float* bias; const float* res; void* C;
  bf16_t* vtD;
  long lda, sAb, sAh;
  long ldw, sWb, sWh;
  long ldr, sRb, sRh;
  long ldc, sCb, sCh;
  long vtN;
  int vtC0, vtDH, vtNH;
  int K, zdiv, cBf, act;
  float scale;
};

template <int MT>
__global__ __launch_bounds__(256) void mma_nt_kernel(MmaNT p) {
  constexpr int FM = MT / 32;          // m-frags per wave (wave covers MT/2 rows)
  constexpr int SM_MAIN = MT * 40 + 128 * 40;
  constexpr int SM_EPI = 64 * 132;
  constexpr int SMSZ = SM_MAIN > SM_EPI ? SM_MAIN : SM_EPI;
  __shared__ bf16_t smem[SMSZ];
  bf16_t* Al = smem;                   // rows padded to 40 bf16
  bf16_t* Wl = smem + MT * 40;
  const int tid = threadIdx.x;
  const int wid = tid >> 6, lane = tid & 63;
  const int wm = wid & 1, wn = wid >> 1;     // waves 2x2 over (M/2, 128/2)
  const int quad = lane >> 4, l16 = lane & 15;
  const int z = blockIdx.z;
  const int zb = z / p.zdiv, zh = z % p.zdiv;
  const long m0 = (long)blockIdx.y * MT;
  const long n0 = (long)blockIdx.x * 128;
  const bf16_t* Ag = p.A + (long)zb * p.sAb + (long)zh * p.sAh + m0 * p.lda;
  const bf16_t* Wg = p.W + (long)zb * p.sWb + (long)zh * p.sWh + n0 * p.ldw;

  f32x4 zero4 = {0.f, 0.f, 0.f, 0.f};
  f32x4 acc[FM][4];
#pragma unroll
  for (int fm = 0; fm < FM; ++fm)
#pragma unroll
    for (int fn = 0; fn < 4; ++fn) acc[fm][fn] = zero4;

  for (int kc = 0; kc < p.K; kc += 32) {
    uint4 areg[MT / 64], wreg[2];
#pragma unroll
    for (int i = 0; i < MT / 64; ++i) {
      int flat = tid + i * 256, r = flat >> 2, cg = flat & 3;
      areg[i] = *(const uint4*)(Ag + (long)r * p.lda + kc + cg * 8);
    }
#pragma unroll
    for (int i = 0; i < 2; ++i) {
      int flat = tid + i * 256, r = flat >> 2, cg = flat & 3;
      wreg[i] = *(const uint4*)(Wg + (long)r * p.ldw + kc + cg * 8);
    }
    __syncthreads();
#pragma unroll
    for (int i = 0; i < MT / 64; ++i) {
      int flat = tid + i * 256, r = flat >> 2, cg = flat & 3;
      *(uint4*)&Al[r * 40 + cg * 8] = areg[i];
    }
#pragma unroll
    for (int i = 0; i < 2; ++i) {
      int flat = tid + i * 256, r = flat >> 2, cg = flat & 3;
      *(uint4*)&Wl[r * 40 + cg * 8] = wreg[i];
    }
    __syncthreads();
    bf16x8 af[FM], wf[4];
#pragma unroll
    for (int fm = 0; fm < FM; ++fm)
      af[fm] = *(const bf16x8*)&Al[(wm * (MT / 2) + fm * 16 + l16) * 40 + quad * 8];
#pragma unroll
    for (int fn = 0; fn < 4; ++fn)
      wf[fn] = *(const bf16x8*)&Wl[(wn * 64 + fn * 16 + l16) * 40 + quad * 8];
#pragma unroll
    for (int fm = 0; fm < FM; ++fm)
#pragma unroll
      for (int fn = 0; fn < 4; ++fn)
        acc[fm][fn] = __builtin_amdgcn_mfma_f32_16x16x32_bf16(af[fm], wf[fn], acc[fm][fn], 0, 0, 0);
  }

  const long cOff = (long)zb * p.sCb + (long)zh * p.sCh;
  const long rOff = (long)zb * p.sRb + (long)zh * p.sRh;
  // ---- epilogue transform in registers ----
#pragma unroll
  for (int fm = 0; fm < FM; ++fm)
#pragma unroll
    for (int fn = 0; fn < 4; ++fn) {
      const long col = n0 + wn * 64 + fn * 16 + l16;
      const float bv = p.bias ? p.bias[col] : 0.f;
#pragma unroll
      for (int r = 0; r < 4; ++r) {
        const long row = m0 + wm * (MT / 2) + fm * 16 + quad * 4 + r;
        float t = acc[fm][fn][r] + bv;
        if (p.act) t = gelu_exact(t);
        t *= p.scale;
        if (p.res) t += p.res[rOff + row * p.ldr + col];
        acc[fm][fn][r] = t;
      }
    }

  if (!p.cBf) {   // fp32 path: per-lane 4B stores (64B sector-aligned per quad-row)
    float* Cf = (float*)p.C + cOff;
#pragma unroll
    for (int fm = 0; fm < FM; ++fm)
#pragma unroll
      for (int fn = 0; fn < 4; ++fn) {
        const long col = n0 + wn * 64 + fn * 16 + l16;
#pragma unroll
        for (int r = 0; r < 4; ++r) {
          const long row = m0 + wm * (MT / 2) + fm * 16 + quad * 4 + r;
          Cf[row * p.ldc + col] = acc[fm][fn][r];
        }
      }
    return;
  }

  // ---- bf16 path: stage 64x128 tile(s) in LDS, store coalesced ----
  constexpr int NPH = MT / 64;
  const int vt = (p.vtD != nullptr) && (n0 >= p.vtC0);
#pragma unroll
  for (int ph = 0; ph < NPH; ++ph) {
    __syncthreads();
    if (NPH == 1 || wm == ph) {
      const int rb = (NPH == 1) ? wm * (MT / 2) : 0;
#pragma unroll
      for (int fm = 0; fm < FM; ++fm)
#pragma unroll
        for (int fn = 0; fn < 4; ++fn)
#pragma unroll
          for (int r = 0; r < 4; ++r)
            smem[(rb + fm * 16 + quad * 4 + r) * 132 + wn * 64 + fn * 16 + l16] =
                f2bf(acc[fm][fn][r]);
    }
    __syncthreads();
    const long row0 = m0 + ph * 64;
    if (!vt) {
      bf16_t* Cb = (bf16_t*)p.C + cOff;
#pragma unroll
      for (int i = 0; i < 4; ++i) {
        int idx = tid + i * 256;
        int rr = idx >> 4, c8 = (idx & 15) * 8;
        uint4 v = *(const uint4*)&smem[rr * 132 + c8];
        *(uint4*)(Cb + (row0 + rr) * p.ldc + n0 + c8) = v;
      }
    } else {
      const long b = row0 / p.vtN, nb = row0 % p.vtN;
#pragma unroll
      for (int i = 0; i < 4; ++i) {
        int idx = tid + i * 256;
        int col = idx >> 3, n8 = (idx & 7) * 8;
        int cv = (int)(n0 - p.vtC0) + col;
        int h = cv / p.vtDH, d = cv % p.vtDH;
        unsigned int pk[4];
#pragma unroll
        for (int j = 0; j < 4; ++j)
          pk[j] = (unsigned int)smem[(n8 + 2 * j) * 132 + col] |
                  ((unsigned int)smem[(n8 + 2 * j + 1) * 132 + col] << 16);
        *(uint4*)(p.vtD + ((long)(b * p.vtNH + h) * p.vtDH + d) * p.vtN + nb + n8) =
            make_uint4(pk[0], pk[1], pk[2], pk[3]);
      }
    }
  }
}

// ---------------- split-KV flash attention, LDS-staged (pass 1) ----------------
struct FlashP2 {
  const bf16_t* Q; const bf16_t* K; const bf16_t* VT; const float* prior;
  float* partO; float* partML;
  long ldq, sQb, sQh;
  long ldk, sKb, sKh;
  long sVz, sPb;
  int nh, N, segN;
  float scale;
};

template <int DH, int HASP>
__global__ __launch_bounds__(256) void flash3_kernel(FlashP2 p) {
  constexpr int KK = DH / 32;       // k-frags over dh (QK^T)
  constexpr int NFO = DH / 16;      // output col frags
  constexpr int KPAD = DH + 8;
  __shared__ bf16_t Kl[64 * KPAD];  // K tile   [64 n-rows][DH]
  __shared__ bf16_t Vl[DH * 72];    // VT tile  [DH rows][64 n-cols]
  __shared__ bf16_t Pl[128 * 72];   // P transit [128 q-rows][64]
  const int tid = threadIdx.x;
  const int w = tid >> 6, lane = tid & 63;
  const int quad = lane >> 4, l16 = lane & 15;
  const int z = blockIdx.z;
  const int zb = z / p.nh, zh = z % p.nh;
  const int qr0 = blockIdx.y * 128 + w * 32;    // wave's first q-row
  const bf16_t* Q = p.Q + (long)zb * p.sQb + (long)zh * p.sQh + (long)qr0 * p.ldq;
  const bf16_t* K = p.K + (long)zb * p.sKb + (long)zh * p.sKh;
  const bf16_t* VT = p.VT + (long)z * p.sVz;

  bf16x8 qf[2][KK];
#pragma unroll
  for (int fm = 0; fm < 2; ++fm)
#pragma unroll
    for (int kk = 0; kk < KK; ++kk)
      qf[fm][kk] = *(const bf16x8*)(Q + (long)(fm * 16 + l16) * p.ldq + kk * 32 + quad * 8);

  f32x4 zero4 = {0.f, 0.f, 0.f, 0.f};
  f32x4 O[2][NFO];
  float m_[2][4], l_[2][4];
#pragma unroll
  for (int fm = 0; fm < 2; ++fm) {
#pragma unroll
    for (int f = 0; f < NFO; ++f) O[fm][f] = zero4;
#pragma unroll
    for (int r = 0; r < 4; ++r) { m_[fm][r] = -1e30f; l_[fm][r] = 0.f; }
  }

  const int k0 = blockIdx.x * p.segN;
  for (int kt = k0; kt < k0 + p.segN; kt += 64) {
    __syncthreads();
    constexpr int KTH = DH / 8;          // threads per K row
#pragma unroll
    for (int i = 0; i < DH / 32; ++i) {
      int flat = tid + i * 256, r = flat / KTH, c = (flat % KTH) * 8;
      *(uint4*)&Kl[r * KPAD + c] = *(const uint4*)(K + (long)(kt + r) * p.ldk + c);
    }
#pragma unroll
    for (int i = 0; i < DH / 32; ++i) {
      int flat = tid + i * 256, r = flat >> 3, c = (flat & 7) * 8;
      *(uint4*)&Vl[r * 72 + c] = *(const uint4*)(VT + (long)r * p.N + kt + c);
    }
    float pr[2][4][4];
    if (HASP) {
#pragma unroll
      for (int fm = 0; fm < 2; ++fm) {
        const float* PR = p.prior + (long)zb * p.sPb +
                          (long)(qr0 + fm * 16 + quad * 4) * p.N + kt;
#pragma unroll
        for (int nf = 0; nf < 4; ++nf)
#pragma unroll
          for (int r = 0; r < 4; ++r)
            pr[fm][nf][r] = PR[(long)r * p.N + nf * 16 + l16];
      }
    }
    __syncthreads();
    f32x4 s[2][4];
#pragma unroll
    for (int nf = 0; nf < 4; ++nf) { s[0][nf] = zero4; s[1][nf] = zero4; }
#pragma unroll
    for (int nf = 0; nf < 4; ++nf)
#pragma unroll
      for (int kk = 0; kk < KK; ++kk) {
        bf16x8 kf = *(const bf16x8*)&Kl[(nf * 16 + l16) * KPAD + kk * 32 + quad * 8];
        s[0][nf] = __builtin_amdgcn_mfma_f32_16x16x32_bf16(qf[0][kk], kf, s[0][nf], 0, 0, 0);
        s[1][nf] = __builtin_amdgcn_mfma_f32_16x16x32_bf16(qf[1][kk], kf, s[1][nf], 0, 0, 0);
      }
    float tm[2][4];
#pragma unroll
    for (int fm = 0; fm < 2; ++fm) {
#pragma unroll
      for (int r = 0; r < 4; ++r) tm[fm][r] = -1e30f;
#pragma unroll
      for (int nf = 0; nf < 4; ++nf)
#pragma unroll
        for (int r = 0; r < 4; ++r) {
          float t = s[fm][nf][r] * p.scale;
          if (HASP) t += pr[fm][nf][r];
          s[fm][nf][r] = t;
          tm[fm][r] = fmaxf(tm[fm][r], t);
        }
    }
#pragma unroll
    for (int off = 1; off < 16; off <<= 1)
#pragma unroll
      for (int fm = 0; fm < 2; ++fm)
#pragma unroll
        for (int r = 0; r < 4; ++r) tm[fm][r] = fmaxf(tm[fm][r], __shfl_xor(tm[fm][r], off));
    float alpha[2][4], rs[2][4];
#pragma unroll
    for (int fm = 0; fm < 2; ++fm)
#pragma unroll
      for (int r = 0; r < 4; ++r) {
        float mn = fmaxf(m_[fm][r], tm[fm][r]);
        alpha[fm][r] = __expf(m_[fm][r] - mn);
        m_[fm][r] = mn;
        rs[fm][r] = 0.f;
      }
#pragma unroll
    for (int fm = 0; fm < 2; ++fm)
#pragma unroll
      for (int nf = 0; nf < 4; ++nf)
#pragma unroll
        for (int r = 0; r < 4; ++r) {
          float pv = __expf(s[fm][nf][r] - m_[fm][r]);
          s[fm][nf][r] = pv;
          rs[fm][r] += pv;
        }
#pragma unroll
    for (int off = 1; off < 16; off <<= 1)
#pragma unroll
      for (int fm = 0; fm < 2; ++fm)
#pragma unroll
        for (int r = 0; r < 4; ++r) rs[fm][r] += __shfl_xor(rs[fm][r], off);
#pragma unroll
    for (int fm = 0; fm < 2; ++fm)
#pragma unroll
      for (int r = 0; r < 4; ++r) l_[fm][r] = l_[fm][r] * alpha[fm][r] + rs[fm][r];
#pragma unroll
    for (int fm = 0; fm < 2; ++fm)
#pragma unroll
      for (int nf = 0; nf < 4; ++nf)
#pragma unroll
        for (int r = 0; r < 4; ++r)
          Pl[(w * 32 + fm * 16 + quad * 4 + r) * 72 + nf * 16 + l16] = f2bf(s[fm][nf][r]);
#pragma unroll
    for (int fm = 0; fm < 2; ++fm)
#pragma unroll
      for (int f = 0; f < NFO; ++f)
#pragma unroll
        for (int r = 0; r < 4; ++r) O[fm][f][r] *= alpha[fm][r];
    bf16x8 pf[2][2];
#pragma unroll
    for (int fm = 0; fm < 2; ++fm)
#pragma unroll
      for (int kk2 = 0; kk2 < 2; ++kk2)
        pf[fm][kk2] = *(const bf16x8*)&Pl[(w * 32 + fm * 16 + l16) * 72 + kk2 * 32 + quad * 8];
#pragma unroll
    for (int f = 0; f < NFO; ++f)
#pragma unroll
      for (int kk2 = 0; kk2 < 2; ++kk2) {
        bf16x8 vf = *(const bf16x8*)&Vl[(f * 16 + l16) * 72 + kk2 * 32 + quad * 8];
        O[0][f] = __builtin_amdgcn_mfma_f32_16x16x32_bf16(pf[0][kk2], vf, O[0][f], 0, 0, 0);
        O[1][f] = __builtin_amdgcn_mfma_f32_16x16x32_bf16(pf[1][kk2], vf, O[1][f], 0, 0, 0);
      }
  }
  const long t = ((long)z * gridDim.y + blockIdx.y) * gridDim.x + blockIdx.x;
  float* PO = p.partO + t * (128 * DH);
  float* PM = p.partML + t * 256;
#pragma unroll
  for (int fm = 0; fm < 2; ++fm) {
#pragma unroll
    for (int f = 0; f < NFO; ++f)
#pragma unroll
      for (int r = 0; r < 4; ++r)
        PO[(long)(w * 32 + fm * 16 + quad * 4 + r) * DH + f * 16 + l16] = O[fm][f][r];
    if (l16 == 0) {
#pragma unroll
      for (int r = 0; r < 4; ++r) {
        PM[(w * 32 + fm * 16 + quad * 4 + r) * 2 + 0] = m_[fm][r];
        PM[(w * 32 + fm * 16 + quad * 4 + r) * 2 + 1] = l_[fm][r];
      }
    }
  }
}

// ---------------- flash pass 2: merge NS segment partials, normalize, store bf16 ----------
struct MergeP {
  const float* partO; const float* partML; bf16_t* C;
  long ldc, sCb;
  int nh, y;
};

template <int DH, int NS>
__global__ __launch_bounds__(256) void fmerge_kernel(MergeP p) {
  const int tid = threadIdx.x;
  const int r = tid >> 1, ch = tid & 1;          // 128 rows x 2 col-halves
  const int blk = blockIdx.x;
  const int z = blk / p.y, qb = blk % p.y;
  const int zb = z / p.nh, zh = z % p.nh;
  const long t0 = (long)blk * NS;
  float mm[NS], wgt[NS];
  float mstar = -1e30f;
#pragma unroll
  for (int s = 0; s < NS; ++s) {
    mm[s] = p.partML[(t0 + s) * 256 + r * 2];
    mstar = fmaxf(mstar, mm[s]);
  }
  float lsum = 0.f;
#pragma unroll
  for (int s = 0; s < NS; ++s) {
    wgt[s] = __expf(mm[s] - mstar);
    lsum += wgt[s] * p.partML[(t0 + s) * 256 + r * 2 + 1];
  }
  const float inv = 1.0f / lsum;
  const int c0 = ch * (DH / 2);
  bf16_t* Cp = p.C + (long)zb * p.sCb + (long)(qb * 128 + r) * p.ldc + (long)zh * DH + c0;
#pragma unroll
  for (int c = 0; c < DH / 2; c += 4) {
    float4 acc = make_float4(0.f, 0.f, 0.f, 0.f);
#pragma unroll
    for (int s = 0; s < NS; ++s) {
      float4 v = *(const float4*)(p.partO + (t0 + s) * (128 * DH) + (long)r * DH + c0 + c);
      acc.x += wgt[s] * v.x; acc.y += wgt[s] * v.y;
      acc.z += wgt[s] * v.z; acc.w += wgt[s] * v.w;
    }
    ushort4 o;
    o.x = f2bf(acc.x * inv); o.y = f2bf(acc.y * inv);
    o.z = f2bf(acc.z * inv); o.w = f2bf(acc.w * inv);
    *(ushort4*)(Cp + c) = o;
  }
}

// ---------------- host ----------------
#define MB(x) ((long)(x) << 20)

extern "C" void kernel_launch(void* const* d_in, const int* in_sizes, int n_in,
                              void* d_out, int out_size, void* d_ws, size_t ws_size,
                              hipStream_t stream) {
  const float* motion      = (const float*)d_in[0];
  const float* scene_feats = (const float*)d_in[2];
  const float* prior       = (const float*)d_in[3];
  const float* ln1_g = (const float*)d_in[4];
  const float* ln1_b = (const float*)d_in[5];
  const float* qkv_w = (const float*)d_in[6];
  const float* qkv_b = (const float*)d_in[7];
  const float* out_w = (const float*)d_in[8];
  const float* out_b = (const float*)d_in[9];
  const float* ln2_g = (const float*)d_in[10];
  const float* ln2_b = (const float*)d_in[11];
  const float* ff1_w = (const float*)d_in[12];
  const float* ff1_b = (const float*)d_in[13];
  const float* ff2_w = (const float*)d_in[14];
  const float* ff2_b = (const float*)d_in[15];
  const float* saq_w = (const float*)d_in[16];
  const float* saq_b = (const float*)d_in[17];
  const float* sakv_w = (const float*)d_in[18];
  const float* sakv_b = (const float*)d_in[19];
  const float* saout_w = (const float*)d_in[20];
  const float* saout_b = (const float*)d_in[21];
  const float* fc1_w = (const float*)d_in[22];
  const float* fc1_b = (const float*)d_in[23];
  const float* fc2_w = (const float*)d_in[24];
  const float* fc2_b = (const float*)d_in[25];

  char* W = (char*)d_ws;
  bf16_t* h_bf    = (bf16_t*)(W + MB(0));    // 4 MB
  float*  x_f     = (float*) (W + MB(4));    // 8 MB
  bf16_t* o_ff    = (bf16_t*)(W + MB(12));   // 4 MB  enc-attn out, then ff1g
  bf16_t* qkv_bf  = (bf16_t*)(W + MB(16));   // 12 MB (Q,K halves; V written to vTe)
  bf16_t* qsa     = (bf16_t*)(W + MB(28));   // 4 MB
  bf16_t* sm_bf   = (bf16_t*)(W + MB(32));   // 4 MB
  bf16_t* cat_bf  = (bf16_t*)(W + MB(36));   // 8 MB  [msca | smf]; pre-enc: enc partML
  bf16_t* fc1g    = (bf16_t*)(W + MB(44));   // 16 MB; pre-fc1: enc partO
  bf16_t* vTe     = (bf16_t*)(W + MB(60));   // 4 MB  enc V^T; post-enc: SA partML
  bf16_t* kv_bf   = (bf16_t*)(W + MB(64));   // 64 MB [32768][1024] (K half valid)
  bf16_t* vT      = (bf16_t*)(W + MB(128));  // 32 MB SA V^T  [32 z][128][4096]
  bf16_t* wbase   = (bf16_t*)(W + MB(160));  // 11.5 MB bf16 weights
  bf16_t* scene_bf= (bf16_t*)(W + MB(172));  // 32 MB; post-kv: SA partO (32 MB)

  float* encO  = (float*)fc1g;               // 16 MB
  float* encML = (float*)cat_bf;             // 0.5 MB
  float* saO   = (float*)scene_bf;           // 32 MB
  float* saML  = (float*)vTe;                // 0.5 MB

  bf16_t* wq   = wbase + 0L;
  bf16_t* wout = wbase + 786432L;
  bf16_t* wff1 = wbase + 1048576L;
  bf16_t* wff2 = wbase + 1310720L;
  bf16_t* wsaq = wbase + 1572864L;
  bf16_t* wskv = wbase + 1835008L;
  bf16_t* wsout= wbase + 2359296L;
  bf16_t* wfc1 = wbase + 2621440L;
  bf16_t* wfc2 = wbase + 4718592L;

  const dim3 B256(256);
  auto cvt = [&](const float* s, bf16_t* d, long n) {
    int n4 = (int)(n / 4);
    f2bf_kernel<<<(n4 + 255) / 256, B256, 0, stream>>>((const float4*)s, (ushort4*)d, n4);
  };
  cvt(qkv_w,  wq,   786432);
  cvt(out_w,  wout, 262144);
  cvt(ff1_w,  wff1, 262144);
  cvt(ff2_w,  wff2, 262144);
  cvt(saq_w,  wsaq, 262144);
  cvt(sakv_w, wskv, 524288);
  cvt(saout_w,wsout,262144);
  cvt(fc1_w,  wfc1, 2097152);
  cvt(fc2_w,  wfc2, 1048576);
  cvt(scene_feats, scene_bf, 16777216);

  // 1. h = LN1(motion)
  ln_kernel<<<1024, B256, 0, stream>>>(motion, ln1_g, ln1_b, h_bf);

  // 2. qkv = h @ qkv_w^T + b  [4096,1536]; V cols (>=1024) transposed to vTe
  { MmaNT p{}; p.scale=1.f; p.zdiv=1; p.cBf=1;
    p.A=h_bf; p.lda=512; p.W=wq; p.ldw=512; p.bias=qkv_b;
    p.C=qkv_bf; p.ldc=1536; p.K=512;
    p.vtD=vTe; p.vtC0=1024; p.vtDH=64; p.vtNH=8; p.vtN=512;
    mma_nt_kernel<128><<<dim3(12,32,1), B256, 0, stream>>>(p); }

  // 3. encoder attention: split flash (NS=2) -> merge
  { FlashP2 p{};
    p.Q=qkv_bf;     p.ldq=1536; p.sQb=786432; p.sQh=64;
    p.K=qkv_bf+512; p.ldk=1536; p.sKb=786432; p.sKh=64;
    p.VT=vTe; p.sVz=32768;
    p.prior=nullptr; p.sPb=0;
    p.partO=encO; p.partML=encML;
    p.nh=8; p.N=512; p.segN=256; p.scale=0.125f;
    flash3_kernel<64,0><<<dim3(2,4,64), B256, 0, stream>>>(p); }
  { MergeP m{}; m.partO=encO; m.partML=encML; m.C=o_ff;
    m.ldc=512; m.sCb=262144; m.nh=8; m.y=4;
    fmerge_kernel<64,2><<<256, B256, 0, stream>>>(m); }

  // 4. x = motion + o @ out_w^T + b   (fp32)
  { MmaNT p{}; p.scale=1.f; p.zdiv=1;
    p.A=o_ff; p.lda=512; p.W=wout; p.ldw=512; p.bias=out_b;
    p.res=motion; p.ldr=512;
    p.C=x_f; p.ldc=512; p.K=512;
    mma_nt_kernel<64><<<dim3(4,64,1), B256, 0, stream>>>(p); }

  // 5. h2 = LN2(x)
  ln_kernel<<<1024, B256, 0, stream>>>(x_f, ln2_g, ln2_b, h_bf);

  // 6. ff1g = gelu(h2 @ ff1_w^T + b)
  { MmaNT p{}; p.scale=1.f; p.zdiv=1; p.cBf=1; p.act=1;
    p.A=h_bf; p.lda=512; p.W=wff1; p.ldw=512; p.bias=ff1_b;
    p.C=o_ff; p.ldc=512; p.K=512;
    mma_nt_kernel<64><<<dim3(4,64,1), B256, 0, stream>>>(p); }

  // 7. msca = x + ff1g @ ff2_w^T + b  -> cat[:, 0:512]
  { MmaNT p{}; p.scale=1.f; p.zdiv=1; p.cBf=1;
    p.A=o_ff; p.lda=512; p.W=wff2; p.ldw=512; p.bias=ff2_b;
    p.res=x_f; p.ldr=512;
    p.C=cat_bf; p.ldc=1024; p.K=512;
    mma_nt_kernel<64><<<dim3(4,64,1), B256, 0, stream>>>(p); }

  // 8. q_sa = (msca @ saq_w^T + b) * 512^-0.5
  { MmaNT p{}; p.zdiv=1; p.cBf=1; p.scale=0.04419417382415922f;
    p.A=cat_bf; p.lda=1024; p.W=wsaq; p.ldw=512; p.bias=saq_b;
    p.C=qsa; p.ldc=512; p.K=512;
    mma_nt_kernel<64><<<dim3(4,64,1), B256, 0, stream>>>(p); }

  // 9. kv = scene @ sakv_w^T + b  [32768,1024]; V cols (>=512) transposed to vT
  { MmaNT p{}; p.scale=1.f; p.zdiv=1; p.cBf=1;
    p.A=scene_bf; p.lda=512; p.W=wskv; p.ldw=512; p.bias=sakv_b;
    p.C=kv_bf; p.ldc=1024; p.K=512;
    p.vtD=vT; p.vtC0=512; p.vtDH=128; p.vtNH=4; p.vtN=4096;
    mma_nt_kernel<128><<<dim3(8,256,1), B256, 0, stream>>>(p); }

  // 10. SA attention: split flash (NS=4, prior prefetched) -> merge
  { FlashP2 p{};
    p.Q=qsa;   p.ldq=128;  p.sQb=262144;  p.sQh=65536;
    p.K=kv_bf; p.ldk=1024; p.sKb=4194304; p.sKh=128;
    p.VT=vT; p.sVz=524288;
    p.prior=prior; p.sPb=2097152;
    p.partO=saO; p.partML=saML;
    p.nh=4; p.N=4096; p.segN=1024; p.scale=1.f;
    flash3_kernel<128,1><<<dim3(4,4,32), B256, 0, stream>>>(p); }
  { MergeP m{}; m.partO=saO; m.partML=saML; m.C=sm_bf;
    m.ldc=512; m.sCb=262144; m.nh=4; m.y=4;
    fmerge_kernel<128,4><<<128, B256, 0, stream>>>(m); }

  // 11. smf = sm @ saout_w^T + b  -> cat[:, 512:1024]
  { MmaNT p{}; p.scale=1.f; p.zdiv=1; p.cBf=1;
    p.A=sm_bf; p.lda=512; p.W=wsout; p.ldw=512; p.bias=saout_b;
    p.C=cat_bf + 512; p.ldc=1024; p.K=512;
    mma_nt_kernel<64><<<dim3(4,64,1), B256, 0, stream>>>(p); }

  // 12. fc1g = gelu(cat @ fc1_w^T + b)   [4096,2048]
  { MmaNT p{}; p.scale=1.f; p.zdiv=1; p.cBf=1; p.act=1;
    p.A=cat_bf; p.lda=1024; p.W=wfc1; p.ldw=1024; p.bias=fc1_b;
    p.C=fc1g; p.ldc=2048; p.K=1024;
    mma_nt_kernel<128><<<dim3(16,32,1), B256, 0, stream>>>(p); }

  // 13. out = fc1g @ fc2_w^T + b  -> d_out fp32
  { MmaNT p{}; p.scale=1.f; p.zdiv=1;
    p.A=fc1g; p.lda=2048; p.W=wfc2; p.ldw=2048; p.bias=fc2_b;
    p.C=d_out; p.ldc=512; p.K=2048;
    mma_nt_kernel<64><<<dim3(4,64,1), B256, 0, stream>>>(p); }
}

// Round 8
// 920.750 us; speedup vs baseline: 1.0284x; 1.0284x over previous
//
#include <hip/hip_runtime.h>

typedef unsigned short bf16_t;
typedef __attribute__((ext_vector_type(8))) short bf16x8;
typedef __attribute__((ext_vector_type(4))) float f32x4;

// ---------------- conversions ----------------
__device__ __forceinline__ float bf2f(bf16_t u) {
  union { unsigned int i; float f; } v; v.i = ((unsigned int)u) << 16; return v.f;
}
__device__ __forceinline__ bf16_t f2bf(float f) {
  union { float f; unsigned int i; } v; v.f = f;
  unsigned int u = v.i;
  u += 0x7fffu + ((u >> 16) & 1u);   // RNE
  return (bf16_t)(u >> 16);
}
__device__ __forceinline__ float gelu_exact(float x) {
  return 0.5f * x * (1.0f + erff(x * 0.7071067811865475f));
}

// ---------------- fp32 -> bf16 convert ----------------
__global__ __launch_bounds__(256) void f2bf_kernel(const float4* __restrict__ s,
                                                   ushort4* __restrict__ d, int n4) {
  int i = blockIdx.x * 256 + threadIdx.x;
  if (i < n4) {
    float4 f = s[i];
    ushort4 u; u.x = f2bf(f.x); u.y = f2bf(f.y); u.z = f2bf(f.z); u.w = f2bf(f.w);
    d[i] = u;
  }
}

// ---------------- LayerNorm: one wave per row of 512, fp32 in -> bf16 out ----------------
__global__ __launch_bounds__(256) void ln_kernel(const float* __restrict__ x,
                                                 const float* __restrict__ g,
                                                 const float* __restrict__ bta,
                                                 bf16_t* __restrict__ y) {
  const int w = threadIdx.x >> 6, lane = threadIdx.x & 63;
  const long row = (long)blockIdx.x * 4 + w;
  const long base = row * 512;
  const int c0 = lane << 2;
  float v[8];
  float4 f0 = *(const float4*)(x + base + c0);
  float4 f1 = *(const float4*)(x + base + 256 + c0);
  v[0]=f0.x; v[1]=f0.y; v[2]=f0.z; v[3]=f0.w;
  v[4]=f1.x; v[5]=f1.y; v[6]=f1.z; v[7]=f1.w;
  float s = 0.f;
#pragma unroll
  for (int c=0;c<8;++c) s += v[c];
#pragma unroll
  for (int o=32;o>0;o>>=1) s += __shfl_xor(s, o);
  const float mean = s * 0.001953125f;
  float ss = 0.f;
#pragma unroll
  for (int c=0;c<8;++c) { float d = v[c]-mean; ss += d*d; }
#pragma unroll
  for (int o=32;o>0;o>>=1) ss += __shfl_xor(ss, o);
  const float rstd = rsqrtf(ss * 0.001953125f + 1e-5f);
  ushort4 o0, o1;
  o0.x = f2bf((v[0]-mean)*rstd*g[c0+0] + bta[c0+0]);
  o0.y = f2bf((v[1]-mean)*rstd*g[c0+1] + bta[c0+1]);
  o0.z = f2bf((v[2]-mean)*rstd*g[c0+2] + bta[c0+2]);
  o0.w = f2bf((v[3]-mean)*rstd*g[c0+3] + bta[c0+3]);
  o1.x = f2bf((v[4]-mean)*rstd*g[256+c0+0] + bta[256+c0+0]);
  o1.y = f2bf((v[5]-mean)*rstd*g[256+c0+1] + bta[256+c0+1]);
  o1.z = f2bf((v[6]-mean)*rstd*g[256+c0+2] + bta[256+c0+2]);
  o1.w = f2bf((v[7]-mean)*rstd*g[256+c0+3] + bta[256+c0+3]);
  *(ushort4*)(y + base + c0) = o0;
  *(ushort4*)(y + base + 256 + c0) = o1;
}

// ---------------- MFMA GEMM  C = A @ W^T  (bf16 in, +bias/gelu/scale/+res fp32) ------------
// grid = (m-blocks, n-blocks, z): flat-ID%8 ~ XCD -> same-XCD blocks share an A-stripe.
// VT=0: coalesced row-major bf16/fp32 store.  VT=1: whole output written transposed per
// head into vtD as [b*vtNH + h][vtDH][vtN] (fuses V^T transpose into the GEMM).
struct MmaNT {
  const bf16_t* A; const bf16_t* W; const float* bias; const float* res; void* C;
  bf16_t* vtD;
  long lda, sAb, sAh;
  long ldw, sWb, sWh;
  long ldr, sRb, sRh;
  long ldc, sCb, sCh;
  long vtN;
  int vtDH, vtNH;
  int K, zdiv, cBf, act;
  float scale;
};

template <int MT, int VT>
__global__ __launch_bounds__(256, MT == 64 ? 5 : 4) void mma_nt_kernel(MmaNT p) {
  constexpr int FM = MT / 32;          // m-frags per wave (wave covers MT/2 rows)
  constexpr int SM_MAIN = (MT + 128) * 40;
  constexpr int ST = MT + 8;           // VT staging col stride (16B-aligned rows)
  constexpr int SM_EPI = VT ? 128 * ST : MT * 132;
  constexpr int SMSZ = SM_MAIN > SM_EPI ? SM_MAIN : SM_EPI;
  __shared__ bf16_t smem[SMSZ];
  bf16_t* Al = smem;                   // rows padded to 40 bf16
  bf16_t* Wl = smem + MT * 40;
  const int tid = threadIdx.x;
  const int wid = tid >> 6, lane = tid & 63;
  const int wm = wid & 1, wn = wid >> 1;     // waves 2x2 over (M/2, 128/2)
  const int quad = lane >> 4, l16 = lane & 15;
  const int z = blockIdx.z;
  const int zb = z / p.zdiv, zh = z % p.zdiv;
  const long m0 = (long)blockIdx.x * MT;
  const long n0 = (long)blockIdx.y * 128;
  const bf16_t* Ag = p.A + (long)zb * p.sAb + (long)zh * p.sAh + m0 * p.lda;
  const bf16_t* Wg = p.W + (long)zb * p.sWb + (long)zh * p.sWh + n0 * p.ldw;

  f32x4 zero4 = {0.f, 0.f, 0.f, 0.f};
  f32x4 acc[FM][4];
#pragma unroll
  for (int fm = 0; fm < FM; ++fm)
#pragma unroll
    for (int fn = 0; fn < 4; ++fn) acc[fm][fn] = zero4;

  for (int kc = 0; kc < p.K; kc += 32) {
    uint4 areg[MT / 64], wreg[2];
#pragma unroll
    for (int i = 0; i < MT / 64; ++i) {
      int flat = tid + i * 256, r = flat >> 2, cg = flat & 3;
      areg[i] = *(const uint4*)(Ag + (long)r * p.lda + kc + cg * 8);
    }
#pragma unroll
    for (int i = 0; i < 2; ++i) {
      int flat = tid + i * 256, r = flat >> 2, cg = flat & 3;
      wreg[i] = *(const uint4*)(Wg + (long)r * p.ldw + kc + cg * 8);
    }
    __syncthreads();
#pragma unroll
    for (int i = 0; i < MT / 64; ++i) {
      int flat = tid + i * 256, r = flat >> 2, cg = flat & 3;
      *(uint4*)&Al[r * 40 + cg * 8] = areg[i];
    }
#pragma unroll
    for (int i = 0; i < 2; ++i) {
      int flat = tid + i * 256, r = flat >> 2, cg = flat & 3;
      *(uint4*)&Wl[r * 40 + cg * 8] = wreg[i];
    }
    __syncthreads();
    bf16x8 af[FM], wf[4];
#pragma unroll
    for (int fm = 0; fm < FM; ++fm)
      af[fm] = *(const bf16x8*)&Al[(wm * (MT / 2) + fm * 16 + l16) * 40 + quad * 8];
#pragma unroll
    for (int fn = 0; fn < 4; ++fn)
      wf[fn] = *(const bf16x8*)&Wl[(wn * 64 + fn * 16 + l16) * 40 + quad * 8];
#pragma unroll
    for (int fm = 0; fm < FM; ++fm)
#pragma unroll
      for (int fn = 0; fn < 4; ++fn)
        acc[fm][fn] = __builtin_amdgcn_mfma_f32_16x16x32_bf16(af[fm], wf[fn], acc[fm][fn], 0, 0, 0);
  }

  const long cOff = (long)zb * p.sCb + (long)zh * p.sCh;
  const long rOff = (long)zb * p.sRb + (long)zh * p.sRh;
  // ---- epilogue transform in registers ----
#pragma unroll
  for (int fm = 0; fm < FM; ++fm)
#pragma unroll
    for (int fn = 0; fn < 4; ++fn) {
      const long col = n0 + wn * 64 + fn * 16 + l16;
      const float bv = p.bias ? p.bias[col] : 0.f;
#pragma unroll
      for (int r = 0; r < 4; ++r) {
        const long row = m0 + wm * (MT / 2) + fm * 16 + quad * 4 + r;
        float t = acc[fm][fn][r] + bv;
        if (p.act) t = gelu_exact(t);
        t *= p.scale;
        if (p.res) t += p.res[rOff + row * p.ldr + col];
        acc[fm][fn][r] = t;
      }
    }

  if (!VT && !p.cBf) {   // fp32 path: per-lane 4B stores (64B per quad-row, full sectors)
    float* Cf = (float*)p.C + cOff;
#pragma unroll
    for (int fm = 0; fm < FM; ++fm)
#pragma unroll
      for (int fn = 0; fn < 4; ++fn) {
        const long col = n0 + wn * 64 + fn * 16 + l16;
#pragma unroll
        for (int r = 0; r < 4; ++r) {
          const long row = m0 + wm * (MT / 2) + fm * 16 + quad * 4 + r;
          Cf[row * p.ldc + col] = acc[fm][fn][r];
        }
      }
    return;
  }

  __syncthreads();   // all waves done reading Al/Wl
  constexpr int NI = MT / 16;          // uint4 stores per thread
  if (!VT) {
    // stage [MT][132] row-major, store coalesced rows
#pragma unroll
    for (int fm = 0; fm < FM; ++fm)
#pragma unroll
      for (int fn = 0; fn < 4; ++fn)
#pragma unroll
        for (int r = 0; r < 4; ++r)
          smem[(wm * (MT / 2) + fm * 16 + quad * 4 + r) * 132 + wn * 64 + fn * 16 + l16] =
              f2bf(acc[fm][fn][r]);
    __syncthreads();
    bf16_t* Cb = (bf16_t*)p.C + cOff;
#pragma unroll
    for (int i = 0; i < NI; ++i) {
      int idx = tid + i * 256;
      int rr = idx >> 4, c8 = (idx & 15) * 8;
      uint4 v = *(const uint4*)&smem[rr * 132 + c8];
      *(uint4*)(Cb + (m0 + rr) * p.ldc + n0 + c8) = v;
    }
  } else {
    // stage [128 cols][MT+8] column-major, store 16B chunks along n (contiguous lines)
#pragma unroll
    for (int fm = 0; fm < FM; ++fm)
#pragma unroll
      for (int fn = 0; fn < 4; ++fn)
#pragma unroll
        for (int r = 0; r < 4; ++r)
          smem[(wn * 64 + fn * 16 + l16) * ST + wm * (MT / 2) + fm * 16 + quad * 4 + r] =
              f2bf(acc[fm][fn][r]);
    __syncthreads();
    const long b = m0 / p.vtN, nb = m0 % p.vtN;
    constexpr int LPC = MT / 8;        // threads per output column
#pragma unroll
    for (int i = 0; i < NI; ++i) {
      int idx = tid + i * 256;
      int col = idx / LPC, n8 = (idx % LPC) * 8;
      int cv = (int)n0 + col;
      int h = cv / p.vtDH, d = cv % p.vtDH;
      uint4 v = *(const uint4*)&smem[col * ST + n8];
      *(uint4*)(p.vtD + ((long)((int)b * p.vtNH + h) * p.vtDH + d) * p.vtN + nb + n8) = v;
    }
  }
}

// ---------------- split-KV flash attention, LDS-staged (pass 1) ----------------
struct FlashP2 {
  const bf16_t* Q; const bf16_t* K; const bf16_t* VT; const float* prior;
  float* partO; float* partML;
  long ldq, sQb, sQh;
  long ldk, sKb, sKh;
  long sVz, sPb;
  int nh, N, segN;
  float scale;
};

template <int DH, int HASP>
__global__ __launch_bounds__(256) void flash3_kernel(FlashP2 p) {
  constexpr int KK = DH / 32;       // k-frags over dh (QK^T)
  constexpr int NFO = DH / 16;      // output col frags
  constexpr int KPAD = DH + 8;
  __shared__ bf16_t Kl[64 * KPAD];  // K tile   [64 n-rows][DH]
  __shared__ bf16_t Vl[DH * 72];    // VT tile  [DH rows][64 n-cols]
  __shared__ bf16_t Pl[128 * 72];   // P transit [128 q-rows][64]
  const int tid = threadIdx.x;
  const int w = tid >> 6, lane = tid & 63;
  const int quad = lane >> 4, l16 = lane & 15;
  const int z = blockIdx.z;
  const int zb = z / p.nh, zh = z % p.nh;
  const int qr0 = blockIdx.y * 128 + w * 32;    // wave's first q-row
  const bf16_t* Q = p.Q + (long)zb * p.sQb + (long)zh * p.sQh + (long)qr0 * p.ldq;
  const bf16_t* K = p.K + (long)zb * p.sKb + (long)zh * p.sKh;
  const bf16_t* VT = p.VT + (long)z * p.sVz;

  bf16x8 qf[2][KK];
#pragma unroll
  for (int fm = 0; fm < 2; ++fm)
#pragma unroll
    for (int kk = 0; kk < KK; ++kk)
      qf[fm][kk] = *(const bf16x8*)(Q + (long)(fm * 16 + l16) * p.ldq + kk * 32 + quad * 8);

  f32x4 zero4 = {0.f, 0.f, 0.f, 0.f};
  f32x4 O[2][NFO];
  float m_[2][4], l_[2][4];
#pragma unroll
  for (int fm = 0; fm < 2; ++fm) {
#pragma unroll
    for (int f = 0; f < NFO; ++f) O[fm][f] = zero4;
#pragma unroll
    for (int r = 0; r < 4; ++r) { m_[fm][r] = -1e30f; l_[fm][r] = 0.f; }
  }

  const int k0 = blockIdx.x * p.segN;
  for (int kt = k0; kt < k0 + p.segN; kt += 64) {
    __syncthreads();
    constexpr int KTH = DH / 8;          // threads per K row
#pragma unroll
    for (int i = 0; i < DH / 32; ++i) {
      int flat = tid + i * 256, r = flat / KTH, c = (flat % KTH) * 8;
      *(uint4*)&Kl[r * KPAD + c] = *(const uint4*)(K + (long)(kt + r) * p.ldk + c);
    }
#pragma unroll
    for (int i = 0; i < DH / 32; ++i) {
      int flat = tid + i * 256, r = flat >> 3, c = (flat & 7) * 8;
      *(uint4*)&Vl[r * 72 + c] = *(const uint4*)(VT + (long)r * p.N + kt + c);
    }
    float pr[2][4][4];
    if (HASP) {
#pragma unroll
      for (int fm = 0; fm < 2; ++fm) {
        const float* PR = p.prior + (long)zb * p.sPb +
                          (long)(qr0 + fm * 16 + quad * 4) * p.N + kt;
#pragma unroll
        for (int nf = 0; nf < 4; ++nf)
#pragma unroll
          for (int r = 0; r < 4; ++r)
            pr[fm][nf][r] = PR[(long)r * p.N + nf * 16 + l16];
      }
    }
    __syncthreads();
    f32x4 s[2][4];
#pragma unroll
    for (int nf = 0; nf < 4; ++nf) { s[0][nf] = zero4; s[1][nf] = zero4; }
#pragma unroll
    for (int nf = 0; nf < 4; ++nf)
#pragma unroll
      for (int kk = 0; kk < KK; ++kk) {
        bf16x8 kf = *(const bf16x8*)&Kl[(nf * 16 + l16) * KPAD + kk * 32 + quad * 8];
        s[0][nf] = __builtin_amdgcn_mfma_f32_16x16x32_bf16(qf[0][kk], kf, s[0][nf], 0, 0, 0);
        s[1][nf] = __builtin_amdgcn_mfma_f32_16x16x32_bf16(qf[1][kk], kf, s[1][nf], 0, 0, 0);
      }
    float tm[2][4];
#pragma unroll
    for (int fm = 0; fm < 2; ++fm) {
#pragma unroll
      for (int r = 0; r < 4; ++r) tm[fm][r] = -1e30f;
#pragma unroll
      for (int nf = 0; nf < 4; ++nf)
#pragma unroll
        for (int r = 0; r < 4; ++r) {
          float t = s[fm][nf][r] * p.scale;
          if (HASP) t += pr[fm][nf][r];
          s[fm][nf][r] = t;
          tm[fm][r] = fmaxf(tm[fm][r], t);
        }
    }
#pragma unroll
    for (int off = 1; off < 16; off <<= 1)
#pragma unroll
      for (int fm = 0; fm < 2; ++fm)
#pragma unroll
        for (int r = 0; r < 4; ++r) tm[fm][r] = fmaxf(tm[fm][r], __shfl_xor(tm[fm][r], off));
    float alpha[2][4], rs[2][4];
#pragma unroll
    for (int fm = 0; fm < 2; ++fm)
#pragma unroll
      for (int r = 0; r < 4; ++r) {
        float mn = fmaxf(m_[fm][r], tm[fm][r]);
        alpha[fm][r] = __expf(m_[fm][r] - mn);
        m_[fm][r] = mn;
        rs[fm][r] = 0.f;
      }
#pragma unroll
    for (int fm = 0; fm < 2; ++fm)
#pragma unroll
      for (int nf = 0; nf < 4; ++nf)
#pragma unroll
        for (int r = 0; r < 4; ++r) {
          float pv = __expf(s[fm][nf][r] - m_[fm][r]);
          s[fm][nf][r] = pv;
          rs[fm][r] += pv;
        }
#pragma unroll
    for (int off = 1; off < 16; off <<= 1)
#pragma unroll
      for (int fm = 0; fm < 2; ++fm)
#pragma unroll
        for (int r = 0; r < 4; ++r) rs[fm][r] += __shfl_xor(rs[fm][r], off);
#pragma unroll
    for (int fm = 0; fm < 2; ++fm)
#pragma unroll
      for (int r = 0; r < 4; ++r) l_[fm][r] = l_[fm][r] * alpha[fm][r] + rs[fm][r];
#pragma unroll
    for (int fm = 0; fm < 2; ++fm)
#pragma unroll
      for (int nf = 0; nf < 4; ++nf)
#pragma unroll
        for (int r = 0; r < 4; ++r)
          Pl[(w * 32 + fm * 16 + quad * 4 + r) * 72 + nf * 16 + l16] = f2bf(s[fm][nf][r]);
#pragma unroll
    for (int fm = 0; fm < 2; ++fm)
#pragma unroll
      for (int f = 0; f < NFO; ++f)
#pragma unroll
        for (int r = 0; r < 4; ++r) O[fm][f][r] *= alpha[fm][r];
    bf16x8 pf[2][2];
#pragma unroll
    for (int fm = 0; fm < 2; ++fm)
#pragma unroll
      for (int kk2 = 0; kk2 < 2; ++kk2)
        pf[fm][kk2] = *(const bf16x8*)&Pl[(w * 32 + fm * 16 + l16) * 72 + kk2 * 32 + quad * 8];
#pragma unroll
    for (int f = 0; f < NFO; ++f)
#pragma unroll
      for (int kk2 = 0; kk2 < 2; ++kk2) {
        bf16x8 vf = *(const bf16x8*)&Vl[(f * 16 + l16) * 72 + kk2 * 32 + quad * 8];
        O[0][f] = __builtin_amdgcn_mfma_f32_16x16x32_bf16(pf[0][kk2], vf, O[0][f], 0, 0, 0);
        O[1][f] = __builtin_amdgcn_mfma_f32_16x16x32_bf16(pf[1][kk2], vf, O[1][f], 0, 0, 0);
      }
  }
  const long t = ((long)z * gridDim.y + blockIdx.y) * gridDim.x + blockIdx.x;
  float* PO = p.partO + t * (128 * DH);
  float* PM = p.partML + t * 256;
#pragma unroll
  for (int fm = 0; fm < 2; ++fm) {
#pragma unroll
    for (int f = 0; f < NFO; ++f)
#pragma unroll
      for (int r = 0; r < 4; ++r)
        PO[(long)(w * 32 + fm * 16 + quad * 4 + r) * DH + f * 16 + l16] = O[fm][f][r];
    if (l16 == 0) {
#pragma unroll
      for (int r = 0; r < 4; ++r) {
        PM[(w * 32 + fm * 16 + quad * 4 + r) * 2 + 0] = m_[fm][r];
        PM[(w * 32 + fm * 16 + quad * 4 + r) * 2 + 1] = l_[fm][r];
      }
    }
  }
}

// ---------------- flash pass 2: merge NS segment partials, normalize, store bf16 ----------
struct MergeP {
  const float* partO; const float* partML; bf16_t* C;
  long ldc, sCb;
  int nh, y;
};

template <int DH, int NS>
__global__ __launch_bounds__(256) void fmerge_kernel(MergeP p) {
  const int tid = threadIdx.x;
  const int r = tid >> 1, ch = tid & 1;          // 128 rows x 2 col-halves
  const int blk = blockIdx.x;
  const int z = blk / p.y, qb = blk % p.y;
  const int zb = z / p.nh, zh = z % p.nh;
  const long t0 = (long)blk * NS;
  float mm[NS], wgt[NS];
  float mstar = -1e30f;
#pragma unroll
  for (int s = 0; s < NS; ++s) {
    mm[s] = p.partML[(t0 + s) * 256 + r * 2];
    mstar = fmaxf(mstar, mm[s]);
  }
  float lsum = 0.f;
#pragma unroll
  for (int s = 0; s < NS; ++s) {
    wgt[s] = __expf(mm[s] - mstar);
    lsum += wgt[s] * p.partML[(t0 + s) * 256 + r * 2 + 1];
  }
  const float inv = 1.0f / lsum;
  const int c0 = ch * (DH / 2);
  bf16_t* Cp = p.C + (long)zb * p.sCb + (long)(qb * 128 + r) * p.ldc + (long)zh * DH + c0;
#pragma unroll
  for (int c = 0; c < DH / 2; c += 4) {
    float4 acc = make_float4(0.f, 0.f, 0.f, 0.f);
#pragma unroll
    for (int s = 0; s < NS; ++s) {
      float4 v = *(const float4*)(p.partO + (t0 + s) * (128 * DH) + (long)r * DH + c0 + c);
      acc.x += wgt[s] * v.x; acc.y += wgt[s] * v.y;
      acc.z += wgt[s] * v.z; acc.w += wgt[s] * v.w;
    }
    ushort4 o;
    o.x = f2bf(acc.x * inv); o.y = f2bf(acc.y * inv);
    o.z = f2bf(acc.z * inv); o.w = f2bf(acc.w * inv);
    *(ushort4*)(Cp + c) = o;
  }
}

// ---------------- host ----------------
#define MB(x) ((long)(x) << 20)

extern "C" void kernel_launch(void* const* d_in, const int* in_sizes, int n_in,
                              void* d_out, int out_size, void* d_ws, size_t ws_size,
                              hipStream_t stream) {
  const float* motion      = (const float*)d_in[0];
  const float* scene_feats = (const float*)d_in[2];
  const float* prior       = (const float*)d_in[3];
  const float* ln1_g = (const float*)d_in[4];
  const float* ln1_b = (const float*)d_in[5];
  const float* qkv_w = (const float*)d_in[6];
  const float* qkv_b = (const float*)d_in[7];
  const float* out_w = (const float*)d_in[8];
  const float* out_b = (const float*)d_in[9];
  const float* ln2_g = (const float*)d_in[10];
  const float* ln2_b = (const float*)d_in[11];
  const float* ff1_w = (const float*)d_in[12];
  const float* ff1_b = (const float*)d_in[13];
  const float* ff2_w = (const float*)d_in[14];
  const float* ff2_b = (const float*)d_in[15];
  const float* saq_w = (const float*)d_in[16];
  const float* saq_b = (const float*)d_in[17];
  const float* sakv_w = (const float*)d_in[18];
  const float* sakv_b = (const float*)d_in[19];
  const float* saout_w = (const float*)d_in[20];
  const float* saout_b = (const float*)d_in[21];
  const float* fc1_w = (const float*)d_in[22];
  const float* fc1_b = (const float*)d_in[23];
  const float* fc2_w = (const float*)d_in[24];
  const float* fc2_b = (const float*)d_in[25];

  char* W = (char*)d_ws;
  bf16_t* h_bf    = (bf16_t*)(W + MB(0));    // 4 MB
  float*  x_f     = (float*) (W + MB(4));    // 8 MB
  bf16_t* o_ff    = (bf16_t*)(W + MB(12));   // 4 MB  enc-attn out, then ff1g
  bf16_t* qk_bf   = (bf16_t*)(W + MB(16));   // 8 MB  [4096][1024] Q|K
  bf16_t* qsa     = (bf16_t*)(W + MB(28));   // 4 MB
  bf16_t* sm_bf   = (bf16_t*)(W + MB(32));   // 4 MB
  bf16_t* cat_bf  = (bf16_t*)(W + MB(36));   // 8 MB  [msca | smf]; pre-enc: enc partML
  bf16_t* fc1g    = (bf16_t*)(W + MB(44));   // 16 MB; pre-fc1: enc partO
  bf16_t* vTe     = (bf16_t*)(W + MB(60));   // 4 MB  enc V^T; post-enc: SA partML
  bf16_t* kv_bf   = (bf16_t*)(W + MB(64));   // 32 MB SA K [32768][512] dense
  bf16_t* vT      = (bf16_t*)(W + MB(128));  // 32 MB SA V^T  [32 z][128][4096]
  bf16_t* wbase   = (bf16_t*)(W + MB(160));  // 11.5 MB bf16 weights
  bf16_t* scene_bf= (bf16_t*)(W + MB(172));  // 32 MB; post-kv: SA partO (32 MB)

  float* encO  = (float*)fc1g;               // 16 MB
  float* encML = (float*)cat_bf;             // 0.5 MB
  float* saO   = (float*)scene_bf;           // 32 MB
  float* saML  = (float*)vTe;                // 0.5 MB

  bf16_t* wq   = wbase + 0L;
  bf16_t* wout = wbase + 786432L;
  bf16_t* wff1 = wbase + 1048576L;
  bf16_t* wff2 = wbase + 1310720L;
  bf16_t* wsaq = wbase + 1572864L;
  bf16_t* wskv = wbase + 1835008L;
  bf16_t* wsout= wbase + 2359296L;
  bf16_t* wfc1 = wbase + 2621440L;
  bf16_t* wfc2 = wbase + 4718592L;

  const dim3 B256(256);
  auto cvt = [&](const float* s, bf16_t* d, long n) {
    int n4 = (int)(n / 4);
    f2bf_kernel<<<(n4 + 255) / 256, B256, 0, stream>>>((const float4*)s, (ushort4*)d, n4);
  };
  cvt(qkv_w,  wq,   786432);
  cvt(out_w,  wout, 262144);
  cvt(ff1_w,  wff1, 262144);
  cvt(ff2_w,  wff2, 262144);
  cvt(saq_w,  wsaq, 262144);
  cvt(sakv_w, wskv, 524288);
  cvt(saout_w,wsout,262144);
  cvt(fc1_w,  wfc1, 2097152);
  cvt(fc2_w,  wfc2, 1048576);
  cvt(scene_feats, scene_bf, 16777216);

  // 1. h = LN1(motion)
  ln_kernel<<<1024, B256, 0, stream>>>(motion, ln1_g, ln1_b, h_bf);

  // 2a. qk = h @ qkv_w[0:1024]^T + b  -> qk_bf [4096][1024]
  { MmaNT p{}; p.scale=1.f; p.zdiv=1; p.cBf=1;
    p.A=h_bf; p.lda=512; p.W=wq; p.ldw=512; p.bias=qkv_b;
    p.C=qk_bf; p.ldc=1024; p.K=512;
    mma_nt_kernel<128,0><<<dim3(32,8,1), B256, 0, stream>>>(p); }
  // 2b. v = h @ qkv_w[1024:1536]^T + b  -> vTe transposed [64 z][64][512]
  { MmaNT p{}; p.scale=1.f; p.zdiv=1; p.cBf=1;
    p.A=h_bf; p.lda=512; p.W=wq+524288; p.ldw=512; p.bias=qkv_b+1024;
    p.vtD=vTe; p.vtDH=64; p.vtNH=8; p.vtN=512; p.K=512;
    mma_nt_kernel<128,1><<<dim3(32,4,1), B256, 0, stream>>>(p); }

  // 3. encoder attention: split flash (NS=2) -> merge
  { FlashP2 p{};
    p.Q=qk_bf;     p.ldq=1024; p.sQb=524288; p.sQh=64;
    p.K=qk_bf+512; p.ldk=1024; p.sKb=524288; p.sKh=64;
    p.VT=vTe; p.sVz=32768;
    p.prior=nullptr; p.sPb=0;
    p.partO=encO; p.partML=encML;
    p.nh=8; p.N=512; p.segN=256; p.scale=0.125f;
    flash3_kernel<64,0><<<dim3(2,4,64), B256, 0, stream>>>(p); }
  { MergeP m{}; m.partO=encO; m.partML=encML; m.C=o_ff;
    m.ldc=512; m.sCb=262144; m.nh=8; m.y=4;
    fmerge_kernel<64,2><<<256, B256, 0, stream>>>(m); }

  // 4. x = motion + o @ out_w^T + b   (fp32)
  { MmaNT p{}; p.scale=1.f; p.zdiv=1;
    p.A=o_ff; p.lda=512; p.W=wout; p.ldw=512; p.bias=out_b;
    p.res=motion; p.ldr=512;
    p.C=x_f; p.ldc=512; p.K=512;
    mma_nt_kernel<64,0><<<dim3(64,4,1), B256, 0, stream>>>(p); }

  // 5. h2 = LN2(x)
  ln_kernel<<<1024, B256, 0, stream>>>(x_f, ln2_g, ln2_b, h_bf);

  // 6. ff1g = gelu(h2 @ ff1_w^T + b)
  { MmaNT p{}; p.scale=1.f; p.zdiv=1; p.cBf=1; p.act=1;
    p.A=h_bf; p.lda=512; p.W=wff1; p.ldw=512; p.bias=ff1_b;
    p.C=o_ff; p.ldc=512; p.K=512;
    mma_nt_kernel<64,0><<<dim3(64,4,1), B256, 0, stream>>>(p); }

  // 7. msca = x + ff1g @ ff2_w^T + b  -> cat[:, 0:512]
  { MmaNT p{}; p.scale=1.f; p.zdiv=1; p.cBf=1;
    p.A=o_ff; p.lda=512; p.W=wff2; p.ldw=512; p.bias=ff2_b;
    p.res=x_f; p.ldr=512;
    p.C=cat_bf; p.ldc=1024; p.K=512;
    mma_nt_kernel<64,0><<<dim3(64,4,1), B256, 0, stream>>>(p); }

  // 8. q_sa = (msca @ saq_w^T + b) * 512^-0.5
  { MmaNT p{}; p.zdiv=1; p.cBf=1; p.scale=0.04419417382415922f;
    p.A=cat_bf; p.lda=1024; p.W=wsaq; p.ldw=512; p.bias=saq_b;
    p.C=qsa; p.ldc=512; p.K=512;
    mma_nt_kernel<64,0><<<dim3(64,4,1), B256, 0, stream>>>(p); }

  // 9a. k = scene @ sakv_w[0:512]^T + b  -> kv_bf [32768][512] dense
  { MmaNT p{}; p.scale=1.f; p.zdiv=1; p.cBf=1;
    p.A=scene_bf; p.lda=512; p.W=wskv; p.ldw=512; p.bias=sakv_b;
    p.C=kv_bf; p.ldc=512; p.K=512;
    mma_nt_kernel<128,0><<<dim3(256,4,1), B256, 0, stream>>>(p); }
  // 9b. v = scene @ sakv_w[512:1024]^T + b  -> vT transposed [32 z][128][4096]
  { MmaNT p{}; p.scale=1.f; p.zdiv=1; p.cBf=1;
    p.A=scene_bf; p.lda=512; p.W=wskv+262144; p.ldw=512; p.bias=sakv_b+512;
    p.vtD=vT; p.vtDH=128; p.vtNH=4; p.vtN=4096; p.K=512;
    mma_nt_kernel<128,1><<<dim3(256,4,1), B256, 0, stream>>>(p); }

  // 10. SA attention: split flash (NS=4, prior prefetched) -> merge
  { FlashP2 p{};
    p.Q=qsa;   p.ldq=128;  p.sQb=262144;  p.sQh=65536;
    p.K=kv_bf; p.ldk=512;  p.sKb=2097152; p.sKh=128;
    p.VT=vT; p.sVz=524288;
    p.prior=prior; p.sPb=2097152;
    p.partO=saO; p.partML=saML;
    p.nh=4; p.N=4096; p.segN=1024; p.scale=1.f;
    flash3_kernel<128,1><<<dim3(4,4,32), B256, 0, stream>>>(p); }
  { MergeP m{}; m.partO=saO; m.partML=saML; m.C=sm_bf;
    m.ldc=512; m.sCb=262144; m.nh=4; m.y=4;
    fmerge_kernel<128,4><<<128, B256, 0, stream>>>(m); }

  // 11. smf = sm @ saout_w^T + b  -> cat[:, 512:1024]
  { MmaNT p{}; p.scale=1.f; p.zdiv=1; p.cBf=1;
    p.A=sm_bf; p.lda=512; p.W=wsout; p.ldw=512; p.bias=saout_b;
    p.C=cat_bf + 512; p.ldc=1024; p.K=512;
    mma_nt_kernel<64,0><<<dim3(64,4,1), B256, 0, stream>>>(p); }

  // 12. fc1g = gelu(cat @ fc1_w^T + b)   [4096,2048]
  { MmaNT p{}; p.scale=1.f; p.zdiv=1; p.cBf=1; p.act=1;
    p.A=cat_bf; p.lda=1024; p.W=wfc1; p.ldw=1024; p.bias=fc1_b;
    p.C=fc1g; p.ldc=2048; p.K=1024;
    mma_nt_kernel<128,0><<<dim3(32,16,1), B256, 0, stream>>>(p); }

  // 13. out = fc1g @ fc2_w^T + b  -> d_out fp32
  { MmaNT p{}; p.scale=1.f; p.zdiv=1;
    p.A=fc1g; p.lda=2048; p.W=wfc2; p.ldw=2048; p.bias=fc2_b;
    p.C=d_out; p.ldc=512; p.K=2048;
    mma_nt_kernel<64,0><<<dim3(64,4,1), B256, 0, stream>>>(p); }
}